// Round 4
// baseline (4075.054 us; speedup 1.0000x reference)
//
#include <hip/hip_runtime.h>
#include <hip/hip_bf16.h>

#define B_   1024
#define H_   512
#define L_   256
#define O_   128
#define SEQ_ 100
#define TE_  200
#define RS   72    // LDS row stride (ushorts) for 64-wide bf16 tiles (+8 pad)
#define AR   264   // LDS row stride (ushorts) for 256-wide bf16 tiles (+8 pad)

typedef __attribute__((ext_vector_type(8))) short short8;
typedef __attribute__((ext_vector_type(4))) float f32x4;

__device__ __forceinline__ float sigmoidf_(float x) { return 1.f / (1.f + __expf(-x)); }
__device__ __forceinline__ float tanhf_(float x) { return 1.f - 2.f / (__expf(2.f * x) + 1.f); }
__device__ __forceinline__ unsigned short f2bf(float x) {
    union { float f; unsigned u; } c; c.f = x;
    unsigned r = c.u + 0x7fffu + ((c.u >> 16) & 1u);   // RNE
    return (unsigned short)(r >> 16);
}
__device__ __forceinline__ unsigned relu2bf(unsigned x) {
    unsigned hi = x & 0xFFFF0000u, lo = x & 0x0000FFFFu;
    if (x & 0x80000000u) hi = 0u;
    if (x & 0x00008000u) lo = 0u;
    return hi | lo;
}
__device__ __forceinline__ uint4 relu8bf(uint4 v) {
    v.x = relu2bf(v.x); v.y = relu2bf(v.y); v.z = relu2bf(v.z); v.w = relu2bf(v.w);
    return v;
}

// ---------------------------------------------------------------------------
__global__ void k_zero(int* __restrict__ p, int n) {
    int i = blockIdx.x * 256 + threadIdx.x;
    if (i < n) p[i] = 0;
}

// ---------------------------------------------------------------------------
__global__ void k_cvt(const float* __restrict__ s, unsigned short* __restrict__ d, int n4) {
    int i = blockIdx.x * 256 + threadIdx.x;
    if (i < n4) {
        float4 v = ((const float4*)s)[i];
        ushort4 o; o.x = f2bf(v.x); o.y = f2bf(v.y); o.z = f2bf(v.z); o.w = f2bf(v.w);
        ((ushort4*)d)[i] = o;
    }
}

// ---------------------------------------------------------------------------
// Pack LSTM weights: Wcat[n'=j*4+g][k 0..1023] bf16 (k<512: W_ih, else W_hh),
// biasp[n'] = b_ih + b_hh.
// ---------------------------------------------------------------------------
__global__ void k_pack_w(const float* __restrict__ Wih, const float* __restrict__ Whh,
                         const float* __restrict__ bih, const float* __restrict__ bhh,
                         unsigned short* __restrict__ Wcat, float* __restrict__ biasp) {
    int np = blockIdx.x;              // 0..2047
    int j = np >> 2, g = np & 3;
    int sr = g * H_ + j;
    int t = threadIdx.x;
    const float* src = (t < 128) ? (Wih + (size_t)sr * H_) : (Whh + (size_t)sr * H_);
    int idx = (t < 128) ? t : (t - 128);
    float4 v = ((const float4*)src)[idx];
    ushort4 o; o.x = f2bf(v.x); o.y = f2bf(v.y); o.z = f2bf(v.z); o.w = f2bf(v.w);
    ((ushort4*)(Wcat + (size_t)np * 1024))[t] = o;
    if (t == 0) biasp[np] = bih[sr] + bhh[sr];
}

// ---------------------------------------------------------------------------
__global__ void k_x0(const float* __restrict__ start, const float* __restrict__ Wemb,
                     const float* __restrict__ bemb, unsigned short* __restrict__ x0) {
    int j = blockIdx.x * 256 + threadIdx.x;
    if (j < H_) {
        float s = bemb[j];
        const float* wp = Wemb + (size_t)j * O_;
        #pragma unroll 4
        for (int o = 0; o < O_; ++o) s += start[o] * wp[o];
        x0[j] = f2bf(s);
    }
}

// ---------------------------------------------------------------------------
// fp32 tiled init projection with leaky_relu; writes fp32 and/or bf16.
// ---------------------------------------------------------------------------
__global__ __launch_bounds__(256) void k_proj_act(
    const float* __restrict__ A, const float* __restrict__ W,
    const float* __restrict__ bias, float* __restrict__ outf,
    unsigned short* __restrict__ outbf, int M, int N, int K)
{
    __shared__ __align__(16) float As[16][68];
    __shared__ __align__(16) float Bs[16][68];
    const int tid = threadIdx.x;
    const int tx = tid & 15, ty = tid >> 4;
    const int m0 = blockIdx.y * 64, n0 = blockIdx.x * 64;
    float acc[4][4] = {};
    for (int kt = 0; kt < K; kt += 16) {
        int m = tid >> 2, k4 = (tid & 3) * 4;
        float4 av = *(const float4*)(A + (size_t)(m0 + m) * K + kt + k4);
        As[k4 + 0][m] = av.x; As[k4 + 1][m] = av.y; As[k4 + 2][m] = av.z; As[k4 + 3][m] = av.w;
        float4 bv = *(const float4*)(W + (size_t)(n0 + m) * K + kt + k4);
        Bs[k4 + 0][m] = bv.x; Bs[k4 + 1][m] = bv.y; Bs[k4 + 2][m] = bv.z; Bs[k4 + 3][m] = bv.w;
        __syncthreads();
        #pragma unroll
        for (int kk = 0; kk < 16; ++kk) {
            float4 a = *(const float4*)&As[kk][ty * 4];
            float4 b = *(const float4*)&Bs[kk][tx * 4];
            float aa[4] = {a.x, a.y, a.z, a.w}, bb[4] = {b.x, b.y, b.z, b.w};
            #pragma unroll
            for (int i = 0; i < 4; ++i)
                #pragma unroll
                for (int j = 0; j < 4; ++j) acc[i][j] += aa[i] * bb[j];
        }
        __syncthreads();
    }
    #pragma unroll
    for (int i = 0; i < 4; ++i) {
        int m = m0 + ty * 4 + i;
        #pragma unroll
        for (int j = 0; j < 4; ++j) {
            int n = n0 + tx * 4 + j;
            float v = acc[i][j] + bias[n];
            v = v > 0.f ? v : 0.01f * v;
            if (outf)  outf[(size_t)m * N + n] = v;
            if (outbf) outbf[(size_t)m * N + n] = f2bf(v);
        }
    }
}

// ---------------------------------------------------------------------------
// PERSISTENT LSTM: all 100 steps in one kernel. Grid 32 x 16 (n-tile, m-tile),
// 256 threads. Per-m0 group barrier (32 blocks) via agent-scope atomics.
// c kept in registers for the whole recurrence. Wcat stays L2-resident.
// ---------------------------------------------------------------------------
__global__ __launch_bounds__(256, 2) void k_lstm_persist(
    const unsigned short* __restrict__ x0,
    const unsigned short* __restrict__ h0,
    unsigned short* __restrict__ hist,
    const unsigned short* __restrict__ Wcat,
    const float* __restrict__ biasp,
    const float* __restrict__ c0,
    float* __restrict__ hT_out,
    float* __restrict__ cT_out,
    int* __restrict__ bar)
{
    __shared__ __align__(16) unsigned short As[64 * RS];
    __shared__ __align__(16) unsigned short Bs[64 * RS];
    __shared__ __align__(16) float Gt[64 * 69];
    const int tid = threadIdx.x;
    const int lane = tid & 63, w = tid >> 6;
    const int q = lane >> 4, ln = lane & 15;
    const int wrow = w & 1, wcol = w >> 1;
    const int n0 = blockIdx.x * 64;      // 32 gate-col tiles
    const int m0 = blockIdx.y * 64;      // 16 batch tiles
    int* cnt = bar + blockIdx.y * 32;    // 128 B per group counter
    const int r0 = tid >> 3, cc = (tid & 7) * 8;

    // per-thread epilogue coordinates (fixed all steps)
    const int jj = tid & 15;
    const int j = (n0 >> 2) + jj;
    const float b_i = biasp[n0 + jj * 4 + 0];
    const float b_f = biasp[n0 + jj * 4 + 1];
    const float b_g = biasp[n0 + jj * 4 + 2];
    const float b_o = biasp[n0 + jj * 4 + 3];
    float cr[4];
    #pragma unroll
    for (int l = 0; l < 4; ++l) {
        int m = (tid >> 4) + l * 16;
        cr[l] = c0[(size_t)(m0 + m) * H_ + j];
    }
    const unsigned short* wb0 = Wcat + (size_t)(n0 + r0) * 1024 + cc;
    const unsigned short* wb1 = Wcat + (size_t)(n0 + r0 + 32) * 1024 + cc;

    for (int t = 0; t < SEQ_; ++t) {
        const unsigned short* hp = (t == 0) ? h0 : hist + (size_t)(t - 1) * B_ * H_;
        const unsigned short* ap0, *ap1;
        if (t == 0) { ap0 = x0 + cc; ap1 = x0 + cc; }
        else        { ap0 = hp + (size_t)(m0 + r0) * H_ + cc;
                      ap1 = hp + (size_t)(m0 + r0 + 32) * H_ + cc; }
        const unsigned short* hp0 = hp + (size_t)(m0 + r0) * H_ + cc;
        const unsigned short* hp1 = hp + (size_t)(m0 + r0 + 32) * H_ + cc;

        f32x4 acc[2][2] = {};
        uint4 a0 = relu8bf(*(const uint4*)ap0);
        uint4 a1 = relu8bf(*(const uint4*)ap1);
        uint4 b0 = *(const uint4*)wb0;
        uint4 b1 = *(const uint4*)wb1;
        for (int it = 0; it < 16; ++it) {
            __syncthreads();
            *(uint4*)&As[r0 * RS + cc] = a0;
            *(uint4*)&As[(r0 + 32) * RS + cc] = a1;
            *(uint4*)&Bs[r0 * RS + cc] = b0;
            *(uint4*)&Bs[(r0 + 32) * RS + cc] = b1;
            __syncthreads();
            if (it < 15) {
                int kt = (it + 1) * 64;
                if (kt < 512) {
                    a0 = relu8bf(*(const uint4*)(ap0 + kt));
                    a1 = relu8bf(*(const uint4*)(ap1 + kt));
                } else {
                    a0 = *(const uint4*)(hp0 + (kt - 512));
                    a1 = *(const uint4*)(hp1 + (kt - 512));
                }
                b0 = *(const uint4*)(wb0 + kt);
                b1 = *(const uint4*)(wb1 + kt);
            }
            #pragma unroll
            for (int kh = 0; kh < 2; ++kh) {
                short8 af0 = *(const short8*)&As[(wrow * 32 + ln) * RS + kh * 32 + q * 8];
                short8 af1 = *(const short8*)&As[(wrow * 32 + 16 + ln) * RS + kh * 32 + q * 8];
                short8 bf0 = *(const short8*)&Bs[(wcol * 32 + ln) * RS + kh * 32 + q * 8];
                short8 bf1 = *(const short8*)&Bs[(wcol * 32 + 16 + ln) * RS + kh * 32 + q * 8];
                acc[0][0] = __builtin_amdgcn_mfma_f32_16x16x32_bf16(af0, bf0, acc[0][0], 0, 0, 0);
                acc[0][1] = __builtin_amdgcn_mfma_f32_16x16x32_bf16(af0, bf1, acc[0][1], 0, 0, 0);
                acc[1][0] = __builtin_amdgcn_mfma_f32_16x16x32_bf16(af1, bf0, acc[1][0], 0, 0, 0);
                acc[1][1] = __builtin_amdgcn_mfma_f32_16x16x32_bf16(af1, bf1, acc[1][1], 0, 0, 0);
            }
        }
        // C layout: row=(lane>>4)*4+reg, col=lane&15
        #pragma unroll
        for (int mt = 0; mt < 2; ++mt)
            #pragma unroll
            for (int nt = 0; nt < 2; ++nt)
                #pragma unroll
                for (int r = 0; r < 4; ++r)
                    Gt[(wrow * 32 + mt * 16 + q * 4 + r) * 69 + wcol * 32 + nt * 16 + ln] = acc[mt][nt][r];
        __syncthreads();
        unsigned short* hout = hist + (size_t)t * B_ * H_;
        #pragma unroll
        for (int l = 0; l < 4; ++l) {
            int m = (tid >> 4) + l * 16;
            float iv = Gt[m * 69 + jj * 4 + 0] + b_i;
            float fv = Gt[m * 69 + jj * 4 + 1] + b_f;
            float gv = Gt[m * 69 + jj * 4 + 2] + b_g;
            float ov = Gt[m * 69 + jj * 4 + 3] + b_o;
            float cn = sigmoidf_(fv) * cr[l] + sigmoidf_(iv) * tanhf_(gv);
            float hn = sigmoidf_(ov) * tanhf_(cn);
            cr[l] = cn;
            size_t off = (size_t)(m0 + m) * H_ + j;
            hout[off] = f2bf(hn);
            if (t == SEQ_ - 1) { hT_out[off] = hn; cT_out[off] = cn; }
        }
        // group barrier: the 32 blocks sharing m0 rendezvous (release h writes)
        if (t < SEQ_ - 1) {
            __syncthreads();               // drains vmcnt -> h stores in L2
            if (tid == 0) {
                __threadfence();           // L2 writeback to device scope
                __hip_atomic_fetch_add(cnt, 1, __ATOMIC_RELEASE, __HIP_MEMORY_SCOPE_AGENT);
                int target = 32 * (t + 1);
                while (__hip_atomic_load(cnt, __ATOMIC_RELAXED, __HIP_MEMORY_SCOPE_AGENT) < target)
                    __builtin_amdgcn_s_sleep(1);
                __atomic_signal_fence(__ATOMIC_ACQUIRE);
            }
            __syncthreads();
            // no L2 invalidate needed: hist[t] lines were never cached by readers
            // before this point in this launch; launch-boundary acquire covers replays.
        }
    }
}

// ---------------------------------------------------------------------------
// Output projection with register-prefetch. M=102400, N=128, K=512.
// ---------------------------------------------------------------------------
__global__ __launch_bounds__(256) void k_outproj_mfma(
    const unsigned short* __restrict__ hist,
    const unsigned short* __restrict__ Wo,
    const float* __restrict__ bo,
    float* __restrict__ out)
{
    __shared__ __align__(16) unsigned short As[64 * RS];
    __shared__ __align__(16) unsigned short Bs[64 * RS];
    const int tid = threadIdx.x;
    const int lane = tid & 63, w = tid >> 6;
    const int q = lane >> 4, ln = lane & 15;
    const int wrow = w & 1, wcol = w >> 1;
    const int m0 = blockIdx.y * 64, n0 = blockIdx.x * 64;
    const int r0 = tid >> 3, cc = (tid & 7) * 8;
    f32x4 acc[2][2] = {};
    uint4 a0 = *(const uint4*)(hist + (size_t)(m0 + r0) * H_ + cc);
    uint4 a1 = *(const uint4*)(hist + (size_t)(m0 + r0 + 32) * H_ + cc);
    uint4 b0 = *(const uint4*)(Wo + (size_t)(n0 + r0) * H_ + cc);
    uint4 b1 = *(const uint4*)(Wo + (size_t)(n0 + r0 + 32) * H_ + cc);
    for (int it = 0; it < 8; ++it) {
        __syncthreads();
        *(uint4*)&As[r0 * RS + cc] = a0;
        *(uint4*)&As[(r0 + 32) * RS + cc] = a1;
        *(uint4*)&Bs[r0 * RS + cc] = b0;
        *(uint4*)&Bs[(r0 + 32) * RS + cc] = b1;
        __syncthreads();
        if (it < 7) {
            int kt = (it + 1) * 64;
            a0 = *(const uint4*)(hist + (size_t)(m0 + r0) * H_ + kt + cc);
            a1 = *(const uint4*)(hist + (size_t)(m0 + r0 + 32) * H_ + kt + cc);
            b0 = *(const uint4*)(Wo + (size_t)(n0 + r0) * H_ + kt + cc);
            b1 = *(const uint4*)(Wo + (size_t)(n0 + r0 + 32) * H_ + kt + cc);
        }
        #pragma unroll
        for (int kh = 0; kh < 2; ++kh) {
            short8 af0 = *(const short8*)&As[(wrow * 32 + ln) * RS + kh * 32 + q * 8];
            short8 af1 = *(const short8*)&As[(wrow * 32 + 16 + ln) * RS + kh * 32 + q * 8];
            short8 bf0 = *(const short8*)&Bs[(wcol * 32 + ln) * RS + kh * 32 + q * 8];
            short8 bf1 = *(const short8*)&Bs[(wcol * 32 + 16 + ln) * RS + kh * 32 + q * 8];
            acc[0][0] = __builtin_amdgcn_mfma_f32_16x16x32_bf16(af0, bf0, acc[0][0], 0, 0, 0);
            acc[0][1] = __builtin_amdgcn_mfma_f32_16x16x32_bf16(af0, bf1, acc[0][1], 0, 0, 0);
            acc[1][0] = __builtin_amdgcn_mfma_f32_16x16x32_bf16(af1, bf0, acc[1][0], 0, 0, 0);
            acc[1][1] = __builtin_amdgcn_mfma_f32_16x16x32_bf16(af1, bf1, acc[1][1], 0, 0, 0);
        }
    }
    #pragma unroll
    for (int mt = 0; mt < 2; ++mt)
        #pragma unroll
        for (int nt = 0; nt < 2; ++nt) {
            int n = n0 + wcol * 32 + nt * 16 + ln;
            float bv = bo[n];
            #pragma unroll
            for (int r = 0; r < 4; ++r) {
                int row = m0 + wrow * 32 + mt * 16 + q * 4 + r;
                int t = row >> 10, b = row & 1023;
                out[(size_t)b * (SEQ_ * O_) + t * O_ + n] = acc[mt][nt][r] + bv;
            }
        }
}

// ---------------------------------------------------------------------------
// num head, fused fp32->bf16 A staging (once per block), B chunks from L2.
// ---------------------------------------------------------------------------
__global__ __launch_bounds__(256) void k_num_mfma(
    const float* __restrict__ enc,
    const unsigned short* __restrict__ Wseq,
    const float* __restrict__ bseq,
    const float* __restrict__ w2,
    const float* __restrict__ b2,
    float* __restrict__ out)
{
    __shared__ __align__(16) unsigned short As[64 * AR];
    __shared__ __align__(16) unsigned short Bs[64 * AR];
    const int tid = threadIdx.x;
    const int lane = tid & 63, w = tid >> 6;
    const int q = lane >> 4, ln = lane & 15;
    const int wrow = w & 1, wcol = w >> 1;
    const int m0 = blockIdx.x * 64;

    {
        const float* base = enc + (size_t)m0 * L_;
        #pragma unroll 4
        for (int it = 0; it < 16; ++it) {
            int flat = it * 1024 + tid * 4;
            int row = flat >> 8, col = flat & 255;
            float4 v = *(const float4*)(base + flat);
            ushort4 o; o.x = f2bf(v.x); o.y = f2bf(v.y); o.z = f2bf(v.z); o.w = f2bf(v.w);
            *(ushort4*)&As[row * AR + col] = o;
        }
    }
    float partial[2][4] = {};
    for (int nc = 0; nc < 8; ++nc) {
        __syncthreads();
        {
            const unsigned short* bb = Wseq + (size_t)nc * 64 * L_;
            #pragma unroll
            for (int it = 0; it < 8; ++it) {
                int flat = it * 2048 + tid * 8;
                int row = flat >> 8, col = flat & 255;
                *(uint4*)&Bs[row * AR + col] = *(const uint4*)(bb + flat);
            }
        }
        __syncthreads();
        f32x4 acc[2][2] = {};
        #pragma unroll
        for (int kt = 0; kt < 8; ++kt) {
            short8 af0 = *(const short8*)&As[(wrow * 32 + ln) * AR + kt * 32 + q * 8];
            short8 af1 = *(const short8*)&As[(wrow * 32 + 16 + ln) * AR + kt * 32 + q * 8];
            short8 bf0 = *(const short8*)&Bs[(wcol * 32 + ln) * AR + kt * 32 + q * 8];
            short8 bf1 = *(const short8*)&Bs[(wcol * 32 + 16 + ln) * AR + kt * 32 + q * 8];
            acc[0][0] = __builtin_amdgcn_mfma_f32_16x16x32_bf16(af0, bf0, acc[0][0], 0, 0, 0);
            acc[0][1] = __builtin_amdgcn_mfma_f32_16x16x32_bf16(af0, bf1, acc[0][1], 0, 0, 0);
            acc[1][0] = __builtin_amdgcn_mfma_f32_16x16x32_bf16(af1, bf0, acc[1][0], 0, 0, 0);
            acc[1][1] = __builtin_amdgcn_mfma_f32_16x16x32_bf16(af1, bf1, acc[1][1], 0, 0, 0);
        }
        #pragma unroll
        for (int nt = 0; nt < 2; ++nt) {
            int n = nc * 64 + wcol * 32 + nt * 16 + ln;
            float bs = bseq[n], wv = w2[n];
            #pragma unroll
            for (int mt = 0; mt < 2; ++mt)
                #pragma unroll
                for (int r = 0; r < 4; ++r) {
                    float v = acc[mt][nt][r] + bs;
                    v = v > 0.f ? v : 0.01f * v;
                    partial[mt][r] += v * wv;
                }
        }
    }
    __syncthreads();
    float* R = (float*)As;
    #pragma unroll
    for (int mt = 0; mt < 2; ++mt)
        #pragma unroll
        for (int r = 0; r < 4; ++r)
            R[(wrow * 32 + mt * 16 + q * 4 + r) * 33 + wcol * 16 + ln] = partial[mt][r];
    __syncthreads();
    if (tid < 64) {
        float s = b2[0];
        #pragma unroll 8
        for (int k2 = 0; k2 < 32; ++k2) s += R[tid * 33 + k2];
        out[m0 + tid] = fmaxf(s, 0.f);
    }
}

// ---------------------------------------------------------------------------
extern "C" void kernel_launch(void* const* d_in, const int* in_sizes, int n_in,
                              void* d_out, int out_size, void* d_ws, size_t ws_size,
                              hipStream_t stream) {
    const float* enc_out = (const float*)d_in[0];
    const float* enc_hid = (const float*)d_in[1];
    const float* start   = (const float*)d_in[2];
    const float* W_l2h   = (const float*)d_in[3];
    const float* b_l2h   = (const float*)d_in[4];
    const float* W_l2h2  = (const float*)d_in[5];
    const float* b_l2h2  = (const float*)d_in[6];
    const float* W_emb   = (const float*)d_in[7];
    const float* b_emb   = (const float*)d_in[8];
    const float* W_ih    = (const float*)d_in[9];
    const float* W_hh    = (const float*)d_in[10];
    const float* b_ih    = (const float*)d_in[11];
    const float* b_hh    = (const float*)d_in[12];
    const float* W_out_p = (const float*)d_in[13];
    const float* b_out_p = (const float*)d_in[14];
    const float* W_seq   = (const float*)d_in[15];
    const float* b_seq   = (const float*)d_in[16];
    const float* W_seq2  = (const float*)d_in[17];
    const float* b_seq2  = (const float*)d_in[18];

    float* out = (float*)d_out;
    float* out_dec = out;                                   // [B, SEQ, O]
    float* out_hT  = out + (size_t)B_ * SEQ_ * O_;          // [1, B, H]
    float* out_cT  = out_hT + (size_t)B_ * H_;              // [1, B, H]
    float* out_num = out_cT + (size_t)B_ * H_;              // [B, TE, 1]

    char* w = (char*)d_ws;
    unsigned short* hist = (unsigned short*)w;   w += (size_t)SEQ_ * B_ * H_ * 2;
    float* cbuf = (float*)w;                     w += (size_t)B_ * H_ * 4;
    unsigned short* h0_bf = (unsigned short*)w;  w += (size_t)B_ * H_ * 2;
    unsigned short* Wcat = (unsigned short*)w;   w += (size_t)2048 * 1024 * 2;
    float* biasp = (float*)w;                    w += 2048 * 4;
    unsigned short* Wout_bf = (unsigned short*)w; w += (size_t)O_ * H_ * 2;
    unsigned short* Wseq_bf = (unsigned short*)w; w += (size_t)H_ * L_ * 2;
    unsigned short* x0_bf = (unsigned short*)w;   w += 4096;
    int* bar = (int*)w;                           w += 16 * 32 * 4;   // group counters

    // ---- weight prep + barrier-counter zeroing ----
    k_pack_w<<<dim3(2048), dim3(256), 0, stream>>>(W_ih, W_hh, b_ih, b_hh, Wcat, biasp);
    k_cvt<<<dim3((O_ * H_ / 4 + 255) / 256), dim3(256), 0, stream>>>(W_out_p, Wout_bf, O_ * H_ / 4);
    k_cvt<<<dim3((H_ * L_ / 4 + 255) / 256), dim3(256), 0, stream>>>(W_seq, Wseq_bf, H_ * L_ / 4);
    k_x0<<<dim3(2), dim3(256), 0, stream>>>(start, W_emb, b_emb, x0_bf);
    k_zero<<<dim3(2), dim3(256), 0, stream>>>(bar, 16 * 32);

    // ---- init h0 (bf16), c0 (fp32) ----
    dim3 g_init(H_ / 64, B_ / 64);
    k_proj_act<<<g_init, dim3(256), 0, stream>>>(enc_hid, W_l2h,  b_l2h,  nullptr, h0_bf, B_, H_, L_);
    k_proj_act<<<g_init, dim3(256), 0, stream>>>(enc_hid, W_l2h2, b_l2h2, cbuf, nullptr, B_, H_, L_);

    // ---- all 100 LSTM steps in ONE persistent kernel ----
    k_lstm_persist<<<dim3(32, 16), dim3(256), 0, stream>>>(x0_bf, h0_bf, hist, Wcat, biasp,
                                                           cbuf, out_hT, out_cT, bar);

    // ---- batched output projection ----
    k_outproj_mfma<<<dim3(O_ / 64, (SEQ_ * B_) / 64), dim3(256), 0, stream>>>(hist, Wout_bf,
                                                                              b_out_p, out_dec);
    // ---- num head ----
    k_num_mfma<<<dim3((B_ * TE_) / 64), dim3(256), 0, stream>>>(enc_out, Wseq_bf, b_seq,
                                                                W_seq2, b_seq2, out_num);
}